// Round 1
// baseline (1547.074 us; speedup 1.0000x reference)
//
#include <hip/hip_runtime.h>

#define D 128
#define TN 64   // nodes per GEMM block

// Scatter-add x[src] into A[g][dst][:], count degrees.
// One 32-lane group per edge, float4 per lane (128 floats/edge).
__global__ __launch_bounds__(256) void rgc_scatter(
    const float* __restrict__ x, const int* __restrict__ src,
    const int* __restrict__ dst, float* __restrict__ A,
    float* __restrict__ degv, int N, int E, int rel0)
{
  int g = blockIdx.y;
  int t = blockIdx.x * 256 + threadIdx.x;
  int e = t >> 5;
  int c = t & 31;
  if (e >= E) return;
  size_t base = (size_t)(rel0 + g) * E + e;
  int s  = src[base];
  int dd = dst[base];
  float4 v = ((const float4*)(x + (size_t)s * D))[c];
  float* ap = A + ((size_t)g * N + dd) * D + 4 * c;
  atomicAdd(ap + 0, v.x);
  atomicAdd(ap + 1, v.y);
  atomicAdd(ap + 2, v.z);
  atomicAdd(ap + 3, v.w);
  if (c == 0) atomicAdd(&degv[(size_t)g * N + dd], 1.0f);
}

// out[node0..node0+63][0..127] (+)= sum_s in_s @ W_s  (+ x@loopW, relu on last pass)
// flags: bit0 = first pass (write, else accumulate), bit1 = last pass (add self-loop + relu)
__global__ __launch_bounds__(256) void rgc_gemm(
    const float* __restrict__ A, const float* __restrict__ deg,
    const float* __restrict__ W, const float* __restrict__ x,
    const float* __restrict__ loopW, float* __restrict__ out,
    int N, int rel0, int G, int flags)
{
  __shared__ float Wl[D * D];     // 64 KB
  __shared__ float inl[TN * D];   // 32 KB
  int tx = threadIdx.x;
  int node0 = blockIdx.x * TN;
  int c = tx & 31;    // 4-col group -> cols 4c..4c+3
  int sub = tx >> 5;  // 0..7 -> nodes sub*8 .. sub*8+7
  float acc[8][4];
#pragma unroll
  for (int t = 0; t < 8; t++)
#pragma unroll
    for (int j = 0; j < 4; j++) acc[t][j] = 0.f;

  int S = G + ((flags & 2) ? 1 : 0);
  for (int s = 0; s < S; s++) {
    bool is_loop = (s == G);
    const float4* Wsrc =
        (const float4*)(is_loop ? loopW : (W + (size_t)(rel0 + s) * D * D));
#pragma unroll
    for (int i = 0; i < (D * D / 4) / 256; i++)  // 16 iters of float4
      ((float4*)Wl)[tx + i * 256] = Wsrc[tx + i * 256];
    // stage 64 input rows (scaled by 1/clip(deg,1) for relation sources)
    for (int i = tx; i < TN * D / 4; i += 256) {
      int row = i >> 5;
      int c4 = i & 31;
      int node = node0 + row;
      float4 v = make_float4(0.f, 0.f, 0.f, 0.f);
      if (node < N) {
        if (is_loop) {
          v = ((const float4*)(x + (size_t)node * D))[c4];
        } else {
          float sc = 1.0f / fmaxf(deg[(size_t)s * N + node], 1.0f);
          float4 a = ((const float4*)(A + ((size_t)s * N + node) * D))[c4];
          v.x = a.x * sc; v.y = a.y * sc; v.z = a.z * sc; v.w = a.w * sc;
        }
      }
      ((float4*)inl)[i] = v;
    }
    __syncthreads();
#pragma unroll 4
    for (int d = 0; d < D; d++) {
      float4 b = ((const float4*)Wl)[d * 32 + c];
#pragma unroll
      for (int t = 0; t < 8; t++) {
        float a = inl[(sub * 8 + t) * D + d];
        acc[t][0] = fmaf(a, b.x, acc[t][0]);
        acc[t][1] = fmaf(a, b.y, acc[t][1]);
        acc[t][2] = fmaf(a, b.z, acc[t][2]);
        acc[t][3] = fmaf(a, b.w, acc[t][3]);
      }
    }
    __syncthreads();
  }

#pragma unroll
  for (int t = 0; t < 8; t++) {
    int node = node0 + sub * 8 + t;
    if (node >= N) continue;
    float* op = out + (size_t)node * D + 4 * c;
    float4 r = make_float4(acc[t][0], acc[t][1], acc[t][2], acc[t][3]);
    if (!(flags & 1)) {
      float4 p = *(const float4*)op;
      r.x += p.x; r.y += p.y; r.z += p.z; r.w += p.w;
    }
    if (flags & 2) {
      r.x = fmaxf(r.x, 0.f); r.y = fmaxf(r.y, 0.f);
      r.z = fmaxf(r.z, 0.f); r.w = fmaxf(r.w, 0.f);
    }
    *(float4*)op = r;
  }
}

extern "C" void kernel_launch(void* const* d_in, const int* in_sizes, int n_in,
                              void* d_out, int out_size, void* d_ws, size_t ws_size,
                              hipStream_t stream)
{
  const float* x     = (const float*)d_in[0];
  const float* W     = (const float*)d_in[1];
  const float* loopW = (const float*)d_in[2];
  const int*   src   = (const int*)d_in[3];
  const int*   dst   = (const int*)d_in[4];
  float* out = (float*)d_out;

  int N = in_sizes[0] / D;           // 100000
  int R = in_sizes[1] / (D * D);     // 4
  int E = in_sizes[3] / R;           // 160000

  // how many relations fit in workspace at once: A[g][N][D] + deg[g][N]
  size_t per_g = (size_t)N * (D + 1) * sizeof(float);
  int G = R;
  while (G > 1 && (size_t)G * per_g > ws_size) G--;

  for (int rel0 = 0; rel0 < R; rel0 += G) {
    int g = (R - rel0 < G) ? (R - rel0) : G;
    float* A    = (float*)d_ws;
    float* degv = A + (size_t)g * N * D;
    hipMemsetAsync(d_ws, 0, (size_t)g * N * (D + 1) * sizeof(float), stream);
    dim3 sgrid((E * 32 + 255) / 256, g);
    rgc_scatter<<<sgrid, 256, 0, stream>>>(x, src, dst, A, degv, N, E, rel0);
    int flags = (rel0 == 0 ? 1 : 0) | (rel0 + g >= R ? 2 : 0);
    int nblk = (N + TN - 1) / TN;
    rgc_gemm<<<nblk, 256, 0, stream>>>(A, degv, W, x, loopW, out, N, rel0, g, flags);
  }
}

// Round 2
// 975.240 us; speedup vs baseline: 1.5864x; 1.5864x over previous
//
#include <hip/hip_runtime.h>

#define D 128
#define TN 64   // nodes per GEMM tile

// ---------- CSR build ----------

__global__ __launch_bounds__(256) void rgc_hist(
    const int* __restrict__ dst, int* __restrict__ cnt, int N, int E)
{
  int r = blockIdx.y;
  int e = blockIdx.x * 256 + threadIdx.x;
  if (e >= E) return;
  atomicAdd(&cnt[(size_t)r * N + dst[(size_t)r * E + e]], 1);
}

// one block per relation; exclusive scan of cnt -> rowptr (N+1 entries)
__global__ __launch_bounds__(1024) void rgc_scan(
    const int* __restrict__ cnt, int* __restrict__ rowptr, int N, int E)
{
  int r = blockIdx.x;
  const int* c = cnt + (size_t)r * N;
  int* rp = rowptr + (size_t)r * (N + 1);
  __shared__ int buf[1024];
  __shared__ int carry_s;
  int tid = threadIdx.x;
  if (tid == 0) carry_s = 0;
  __syncthreads();
  for (int base = 0; base < N; base += 8192) {
    int c0 = carry_s;
    int v[8];
    int s = 0;
#pragma unroll
    for (int j = 0; j < 8; j++) {
      int i = base + tid * 8 + j;
      v[j] = (i < N) ? c[i] : 0;
      s += v[j];
    }
    buf[tid] = s;
    __syncthreads();
    for (int off = 1; off < 1024; off <<= 1) {
      int t = (tid >= off) ? buf[tid - off] : 0;
      __syncthreads();
      buf[tid] += t;
      __syncthreads();
    }
    int run = c0 + buf[tid] - s;  // exclusive prefix for this thread's chunk
#pragma unroll
    for (int j = 0; j < 8; j++) {
      int i = base + tid * 8 + j;
      if (i < N) rp[i] = run;
      run += v[j];
    }
    int tot = buf[1023];
    __syncthreads();
    if (tid == 0) carry_s = c0 + tot;
    __syncthreads();
  }
  if (tid == 0) rp[N] = E;
}

__global__ __launch_bounds__(256) void rgc_fill(
    const int* __restrict__ src, const int* __restrict__ dst,
    const int* __restrict__ rowptr, int* __restrict__ fill,
    int* __restrict__ esrc, int* __restrict__ edst, int N, int E)
{
  int r = blockIdx.y;
  int e = blockIdx.x * 256 + threadIdx.x;
  if (e >= E) return;
  int d = dst[(size_t)r * E + e];
  int pos = rowptr[(size_t)r * (N + 1) + d] +
            atomicAdd(&fill[(size_t)r * N + d], 1);
  esrc[(size_t)r * E + pos] = src[(size_t)r * E + e];
  edst[(size_t)r * E + pos] = d;
}

// ---------- fused gather + GEMM ----------
// out[tile] = relu( sum_r (gather_mean_r(x)) @ W_r + x @ loopW )

__global__ __launch_bounds__(256) void rgc_fused(
    const float* __restrict__ x, const float* __restrict__ W,
    const float* __restrict__ loopW, const int* __restrict__ rowptr,
    const int* __restrict__ esrc, const int* __restrict__ edst,
    float* __restrict__ out, int N, int R, int E)
{
  __shared__ float Wl[D * D];    // 64 KB
  __shared__ float inl[TN * D];  // 32 KB
  __shared__ float scl[TN];
  int tx = threadIdx.x;
  int node0 = blockIdx.x * TN;
  int c = tx & 31;    // column group: cols 4c..4c+3
  int sub = tx >> 5;  // node group: nodes sub*8..sub*8+7
  float acc[8][4];
#pragma unroll
  for (int t = 0; t < 8; t++)
#pragma unroll
    for (int j = 0; j < 4; j++) acc[t][j] = 0.f;

  for (int s = 0; s <= R; s++) {
    bool is_loop = (s == R);
    // load weight tile (Wl free: previous GEMM ended with a barrier)
    const float4* Wsrc =
        (const float4*)(is_loop ? loopW : (W + (size_t)s * D * D));
#pragma unroll
    for (int i = 0; i < (D * D / 4) / 256; i++)
      ((float4*)Wl)[tx + i * 256] = Wsrc[tx + i * 256];

    if (is_loop) {
      for (int i = tx; i < TN * D / 4; i += 256) {
        int row = i >> 5;
        int c4 = i & 31;
        int node = node0 + row;
        float4 v = make_float4(0.f, 0.f, 0.f, 0.f);
        if (node < N) v = ((const float4*)(x + (size_t)node * D))[c4];
        ((float4*)inl)[i] = v;
      }
      __syncthreads();
    } else {
      // zero input tile
      for (int i = tx; i < TN * D / 4; i += 256)
        ((float4*)inl)[i] = make_float4(0.f, 0.f, 0.f, 0.f);
      __syncthreads();
      // edge-parallel gather: contiguous CSR range for this node tile
      const int* rp = rowptr + (size_t)s * (N + 1);
      int nend = node0 + TN < N ? node0 + TN : N;
      int e0 = rp[node0];
      int e1 = rp[nend];
      for (int e = e0 + (tx >> 5); e < e1; e += 8) {
        int sn = esrc[(size_t)s * E + e];
        int row = edst[(size_t)s * E + e] - node0;
        float4 v = ((const float4*)(x + (size_t)sn * D))[c];
        float* p = &inl[row * D + 4 * c];
        atomicAdd(p + 0, v.x);
        atomicAdd(p + 1, v.y);
        atomicAdd(p + 2, v.z);
        atomicAdd(p + 3, v.w);
      }
      if (tx < TN) {
        int node = node0 + tx;
        float dg = 0.f;
        if (node < N) dg = (float)(rp[node + 1] - rp[node]);
        scl[tx] = 1.0f / fmaxf(dg, 1.0f);
      }
      __syncthreads();
      // scale by 1/deg
      for (int i = tx; i < TN * D / 4; i += 256) {
        float sc = scl[i >> 5];
        float4 t = ((float4*)inl)[i];
        t.x *= sc; t.y *= sc; t.z *= sc; t.w *= sc;
        ((float4*)inl)[i] = t;
      }
      __syncthreads();
    }

    // GEMM accumulate: acc += inl @ Wl
#pragma unroll 4
    for (int d = 0; d < D; d++) {
      float4 b = ((const float4*)Wl)[d * 32 + c];
#pragma unroll
      for (int t = 0; t < 8; t++) {
        float a = inl[(sub * 8 + t) * D + d];
        acc[t][0] = fmaf(a, b.x, acc[t][0]);
        acc[t][1] = fmaf(a, b.y, acc[t][1]);
        acc[t][2] = fmaf(a, b.z, acc[t][2]);
        acc[t][3] = fmaf(a, b.w, acc[t][3]);
      }
    }
    __syncthreads();
  }

#pragma unroll
  for (int t = 0; t < 8; t++) {
    int node = node0 + sub * 8 + t;
    if (node >= N) continue;
    float4 r = make_float4(fmaxf(acc[t][0], 0.f), fmaxf(acc[t][1], 0.f),
                           fmaxf(acc[t][2], 0.f), fmaxf(acc[t][3], 0.f));
    *(float4*)(out + (size_t)node * D + 4 * c) = r;
  }
}

extern "C" void kernel_launch(void* const* d_in, const int* in_sizes, int n_in,
                              void* d_out, int out_size, void* d_ws, size_t ws_size,
                              hipStream_t stream)
{
  const float* x     = (const float*)d_in[0];
  const float* W     = (const float*)d_in[1];
  const float* loopW = (const float*)d_in[2];
  const int*   src   = (const int*)d_in[3];
  const int*   dst   = (const int*)d_in[4];
  float* out = (float*)d_out;

  int N = in_sizes[0] / D;        // 100000
  int R = in_sizes[1] / (D * D);  // 4
  int E = in_sizes[3] / R;        // 160000

  // workspace layout (ints): cnt[R*N] | fill[R*N] | rowptr[R*(N+1)] | esrc[R*E] | edst[R*E]
  int* cnt    = (int*)d_ws;
  int* fill   = cnt + (size_t)R * N;
  int* rowptr = fill + (size_t)R * N;
  int* esrc   = rowptr + (size_t)R * (N + 1);
  int* edst   = esrc + (size_t)R * E;

  hipMemsetAsync(d_ws, 0, (size_t)2 * R * N * sizeof(int), stream);

  dim3 egrid((E + 255) / 256, R);
  rgc_hist<<<egrid, 256, 0, stream>>>(dst, cnt, N, E);
  rgc_scan<<<R, 1024, 0, stream>>>(cnt, rowptr, N, E);
  rgc_fill<<<egrid, 256, 0, stream>>>(src, dst, rowptr, fill, esrc, edst, N, E);

  int nblk = (N + TN - 1) / TN;
  rgc_fused<<<nblk, 256, 0, stream>>>(x, W, loopW, rowptr, esrc, edst, out, N, R, E);
}

// Round 3
// 708.027 us; speedup vs baseline: 2.1851x; 1.3774x over previous
//
#include <hip/hip_runtime.h>

#define D 128
#define TN 64

typedef __attribute__((ext_vector_type(8))) short short8;
typedef __attribute__((ext_vector_type(4))) float f32x4;

__device__ __forceinline__ unsigned int bf16rne(float f) {
  unsigned int b = __float_as_uint(f);
  return (b + 0x7fffu + ((b >> 16) & 1u)) >> 16;
}

// ---- one-time weight prep: W[r][k][c] (+loopW) -> bf16, transposed [c][k], XOR-swizzled ----
__global__ __launch_bounds__(256) void rgc_prep_w(
    const float* __restrict__ W, const float* __restrict__ loopW,
    unsigned short* __restrict__ WT, int R)
{
  int tid = blockIdx.x * 256 + threadIdx.x;
  int s = tid >> 14;          // / (128*128)
  if (s > R) return;
  int rem = tid & 16383;
  int k = rem >> 7;
  int c = rem & 127;          // coalesced read along c
  float v = (s < R) ? W[(size_t)s * D * D + k * D + c] : loopW[k * D + c];
  unsigned int u = bf16rne(v);
  unsigned int off = ((unsigned int)(c * D + k) * 2u) ^ (((unsigned int)(c & 7)) << 4);
  *(unsigned short*)((char*)WT + (size_t)s * D * D * 2 + off) = (unsigned short)u;
}

// ---- histograms: per-node degree + per-tile edge counts ----
__global__ __launch_bounds__(256) void rgc_hist(
    const int* __restrict__ dst, int* __restrict__ degc, int* __restrict__ tcnt,
    int N, int E, int ntiles)
{
  int r = blockIdx.y;
  int e = blockIdx.x * 256 + threadIdx.x;
  if (e >= E) return;
  int d = dst[(size_t)r * E + e];
  atomicAdd(&degc[(size_t)r * N + d], 1);
  atomicAdd(&tcnt[r * ntiles + (d >> 6)], 1);
}

// ---- exclusive scan over M bin counts (single block) ----
__global__ __launch_bounds__(1024) void rgc_scan(
    const int* __restrict__ cnt, int* __restrict__ ptr, int M, int total)
{
  __shared__ int buf[1024];
  __shared__ int carry_s;
  int tid = threadIdx.x;
  if (tid == 0) carry_s = 0;
  __syncthreads();
  for (int base = 0; base < M; base += 8192) {
    int c0 = carry_s;
    int v[8];
    int s = 0;
#pragma unroll
    for (int j = 0; j < 8; j++) {
      int i = base + tid * 8 + j;
      v[j] = (i < M) ? cnt[i] : 0;
      s += v[j];
    }
    buf[tid] = s;
    __syncthreads();
    for (int off = 1; off < 1024; off <<= 1) {
      int t = (tid >= off) ? buf[tid - off] : 0;
      __syncthreads();
      buf[tid] += t;
      __syncthreads();
    }
    int run = c0 + buf[tid] - s;
#pragma unroll
    for (int j = 0; j < 8; j++) {
      int i = base + tid * 8 + j;
      if (i < M) ptr[i] = run;
      run += v[j];
    }
    int tot = buf[1023];
    __syncthreads();
    if (tid == 0) carry_s = c0 + tot;
    __syncthreads();
  }
  if (tid == 0) ptr[M] = total;
}

// ---- bin edges by destination tile (order within bin irrelevant) ----
__global__ __launch_bounds__(256) void rgc_fill(
    const int* __restrict__ src, const int* __restrict__ dst,
    const int* __restrict__ tptr, int* __restrict__ tfill,
    int2* __restrict__ edges, int E, int ntiles)
{
  int r = blockIdx.y;
  int e = blockIdx.x * 256 + threadIdx.x;
  if (e >= E) return;
  int d = dst[(size_t)r * E + e];
  int bin = r * ntiles + (d >> 6);
  int pos = tptr[bin] + atomicAdd(&tfill[bin], 1);
  edges[pos] = make_int2(src[(size_t)r * E + e], d & 63);
}

// ---- fused: gather -> mean -> bf16 -> MFMA accumulate over relations + self-loop -> relu ----
__global__ __launch_bounds__(256) void rgc_fused(
    const float* __restrict__ x, const unsigned short* __restrict__ WT,
    const int* __restrict__ degc, const int* __restrict__ tptr,
    const int2* __restrict__ edges, float* __restrict__ out,
    int N, int R, int ntiles)
{
  __shared__ float inl[TN * D];     // 32 KB fp32 gather tile
  __shared__ char Ab[TN * D * 2];   // 16 KB bf16 A tile (swizzled)
  __shared__ char Wb[D * D * 2];    // 32 KB bf16 W^T tile (swizzled)

  int tx = threadIdx.x;
  int tile = blockIdx.x;
  int node0 = tile * TN;
  int lane = tx & 63;
  int w = tx >> 6;

  f32x4 acc[8];
#pragma unroll
  for (int i = 0; i < 8; i++) acc[i] = (f32x4){0.f, 0.f, 0.f, 0.f};

  for (int s = 0; s <= R; s++) {
    // stage pre-swizzled weights: linear 32 KB copy
    const float4* wsrc = (const float4*)(WT + (size_t)s * D * D);
#pragma unroll
    for (int i = 0; i < 8; i++)
      ((float4*)Wb)[tx + i * 256] = wsrc[tx + i * 256];

    if (s < R) {
#pragma unroll
      for (int i = 0; i < 8; i++)
        ((float4*)inl)[tx + i * 256] = make_float4(0.f, 0.f, 0.f, 0.f);
      __syncthreads();
      // gather: 16-lane groups, one edge per group, 8 cols per lane
      int bin = s * ntiles + tile;
      int e0 = tptr[bin], e1 = tptr[bin + 1];
      int g = tx >> 4, c = tx & 15;
      for (int e = e0 + g; e < e1; e += 16) {
        int2 ed = edges[e];
        const float4* xp = (const float4*)(x + (size_t)ed.x * D);
        float4 v0 = xp[2 * c], v1 = xp[2 * c + 1];
        float* p = &inl[ed.y * D + 8 * c];
        atomicAdd(p + 0, v0.x); atomicAdd(p + 1, v0.y);
        atomicAdd(p + 2, v0.z); atomicAdd(p + 3, v0.w);
        atomicAdd(p + 4, v1.x); atomicAdd(p + 5, v1.y);
        atomicAdd(p + 6, v1.z); atomicAdd(p + 7, v1.w);
      }
      __syncthreads();
      // convert (scaled by 1/clip(deg,1)) -> Ab swizzled bf16
#pragma unroll
      for (int it = 0; it < 4; it++) {
        int i = tx + it * 256;     // 1024 chunks of 8 cols
        int row = i >> 4, c16 = (i & 15);
        int node = node0 + row;
        float sc = 1.f;
        if (node < N) sc = 1.0f / fmaxf((float)degc[(size_t)s * N + node], 1.0f);
        float4 v0 = ((float4*)inl)[i * 2];
        float4 v1 = ((float4*)inl)[i * 2 + 1];
        uint4 u;
        u.x = bf16rne(v0.x * sc) | (bf16rne(v0.y * sc) << 16);
        u.y = bf16rne(v0.z * sc) | (bf16rne(v0.w * sc) << 16);
        u.z = bf16rne(v1.x * sc) | (bf16rne(v1.y * sc) << 16);
        u.w = bf16rne(v1.z * sc) | (bf16rne(v1.w * sc) << 16);
        unsigned int off =
            ((unsigned int)(row * 256 + c16 * 16)) ^ (((unsigned int)(row & 7)) << 4);
        *(uint4*)(Ab + off) = u;
      }
    } else {
      // self-loop: x rows straight to Ab
      __syncthreads();
#pragma unroll
      for (int it = 0; it < 4; it++) {
        int i = tx + it * 256;
        int row = i >> 4, c16 = (i & 15);
        int node = node0 + row;
        uint4 u = make_uint4(0, 0, 0, 0);
        if (node < N) {
          const float4* xp = (const float4*)(x + (size_t)node * D);
          float4 v0 = xp[c16 * 2], v1 = xp[c16 * 2 + 1];
          u.x = bf16rne(v0.x) | (bf16rne(v0.y) << 16);
          u.y = bf16rne(v0.z) | (bf16rne(v0.w) << 16);
          u.z = bf16rne(v1.x) | (bf16rne(v1.y) << 16);
          u.w = bf16rne(v1.z) | (bf16rne(v1.w) << 16);
        }
        unsigned int off =
            ((unsigned int)(row * 256 + c16 * 16)) ^ (((unsigned int)(row & 7)) << 4);
        *(uint4*)(Ab + off) = u;
      }
    }
    __syncthreads();

    // MFMA: wave w owns rows [w*16, w*16+16), all 128 cols
    int rA = w * 16 + (lane & 15);
    unsigned int mA = (unsigned int)((rA & 7) << 4);
    unsigned int kof = (unsigned int)((lane >> 4) * 16);
    short8 afr[4];
#pragma unroll
    for (int kk = 0; kk < 4; kk++)
      afr[kk] = *(const short8*)(Ab + rA * 256 + (((unsigned int)(kk * 64) + kof) ^ mA));
#pragma unroll
    for (int ct = 0; ct < 8; ct++) {
      int rB = ct * 16 + (lane & 15);
      unsigned int mB = (unsigned int)((rB & 7) << 4);
#pragma unroll
      for (int kk = 0; kk < 4; kk++) {
        short8 b = *(const short8*)(Wb + rB * 256 + (((unsigned int)(kk * 64) + kof) ^ mB));
        acc[ct] = __builtin_amdgcn_mfma_f32_16x16x32_bf16(afr[kk], b, acc[ct], 0, 0, 0);
      }
    }
    __syncthreads();
  }

  // epilogue: relu + store (C/D: col=lane&15, row=(lane>>4)*4+reg)
  int colb = lane & 15;
  int rowb = (lane >> 4) * 4;
#pragma unroll
  for (int ct = 0; ct < 8; ct++) {
#pragma unroll
    for (int j = 0; j < 4; j++) {
      int node = node0 + w * 16 + rowb + j;
      if (node < N)
        out[(size_t)node * D + ct * 16 + colb] = fmaxf(acc[ct][j], 0.f);
    }
  }
}

extern "C" void kernel_launch(void* const* d_in, const int* in_sizes, int n_in,
                              void* d_out, int out_size, void* d_ws, size_t ws_size,
                              hipStream_t stream)
{
  const float* x     = (const float*)d_in[0];
  const float* W     = (const float*)d_in[1];
  const float* loopW = (const float*)d_in[2];
  const int*   src   = (const int*)d_in[3];
  const int*   dst   = (const int*)d_in[4];
  float* out = (float*)d_out;

  int N = in_sizes[0] / D;        // 100000
  int R = in_sizes[1] / (D * D);  // 4
  int E = in_sizes[3] / R;        // 160000
  int ntiles = (N + TN - 1) / TN;

  // ws layout (ints): degc[R*N] | tcnt[R*nt] | tfill[R*nt] | tptr[R*nt+1] | pad | edges int2[R*E] | WT u16
  int* degc  = (int*)d_ws;
  int* tcnt  = degc + (size_t)R * N;
  int* tfill = tcnt + (size_t)R * ntiles;
  int* tptr  = tfill + (size_t)R * ntiles;
  size_t off = (size_t)R * N + (size_t)3 * R * ntiles + 1;
  off = (off + 1) & ~(size_t)1;
  int2* edges = (int2*)((int*)d_ws + off);
  unsigned short* WT = (unsigned short*)(edges + (size_t)R * E);

  hipMemsetAsync(d_ws, 0, ((size_t)R * N + (size_t)2 * R * ntiles) * sizeof(int), stream);

  rgc_prep_w<<<((R + 1) * D * D + 255) / 256, 256, 0, stream>>>(W, loopW, WT, R);

  dim3 egrid((E + 255) / 256, R);
  rgc_hist<<<egrid, 256, 0, stream>>>(dst, degc, tcnt, N, E, ntiles);
  rgc_scan<<<1, 1024, 0, stream>>>(tcnt, tptr, R * ntiles, R * E);
  rgc_fill<<<egrid, 256, 0, stream>>>(src, dst, tptr, tfill, edges, E, ntiles);

  rgc_fused<<<ntiles, 256, 0, stream>>>(x, WT, degc, tptr, edges, out, N, R, ntiles);
}

// Round 4
// 657.419 us; speedup vs baseline: 2.3533x; 1.0770x over previous
//
#include <hip/hip_runtime.h>

#define D 128
#define TN 64

typedef __attribute__((ext_vector_type(8))) short short8;
typedef __attribute__((ext_vector_type(4))) float f32x4;

__device__ __forceinline__ unsigned int bf16rne(float f) {
  unsigned int b = __float_as_uint(f);
  return (b + 0x7fffu + ((b >> 16) & 1u)) >> 16;
}

// ---- one-time weight prep: W[r][k][c] (+loopW at index R) -> bf16, transposed, XOR-swizzled ----
__global__ __launch_bounds__(256) void rgc_prep_w(
    const float* __restrict__ W, const float* __restrict__ loopW,
    unsigned short* __restrict__ WT, int R)
{
  int tid = blockIdx.x * 256 + threadIdx.x;
  int s = tid >> 14;
  if (s > R) return;
  int rem = tid & 16383;
  int k = rem >> 7;
  int c = rem & 127;
  float v = (s < R) ? W[(size_t)s * D * D + k * D + c] : loopW[k * D + c];
  unsigned int u = bf16rne(v);
  unsigned int off = ((unsigned int)(c * D + k) * 2u) ^ (((unsigned int)(c & 7)) << 4);
  *(unsigned short*)((char*)WT + (size_t)s * D * D * 2 + off) = (unsigned short)u;
}

// ---- histograms: per-node degree + per-tile edge counts (for relation group) ----
__global__ __launch_bounds__(256) void rgc_hist(
    const int* __restrict__ dst, int* __restrict__ degc, int* __restrict__ tcnt,
    int N, int E, int ntiles, int rel0)
{
  int g = blockIdx.y;
  int e = blockIdx.x * 256 + threadIdx.x;
  if (e >= E) return;
  int d = dst[(size_t)(rel0 + g) * E + e];
  atomicAdd(&degc[(size_t)g * N + d], 1);
  atomicAdd(&tcnt[g * ntiles + (d >> 6)], 1);
}

// ---- exclusive scan over M bin counts (single block; M <= 8192 here) ----
__global__ __launch_bounds__(1024) void rgc_scan(
    const int* __restrict__ cnt, int* __restrict__ ptr, int M, int total)
{
  __shared__ int buf[1024];
  __shared__ int carry_s;
  int tid = threadIdx.x;
  if (tid == 0) carry_s = 0;
  __syncthreads();
  for (int base = 0; base < M; base += 8192) {
    int c0 = carry_s;
    int v[8];
    int s = 0;
#pragma unroll
    for (int j = 0; j < 8; j++) {
      int i = base + tid * 8 + j;
      v[j] = (i < M) ? cnt[i] : 0;
      s += v[j];
    }
    buf[tid] = s;
    __syncthreads();
    for (int off = 1; off < 1024; off <<= 1) {
      int t = (tid >= off) ? buf[tid - off] : 0;
      __syncthreads();
      buf[tid] += t;
      __syncthreads();
    }
    int run = c0 + buf[tid] - s;
#pragma unroll
    for (int j = 0; j < 8; j++) {
      int i = base + tid * 8 + j;
      if (i < M) ptr[i] = run;
      run += v[j];
    }
    int tot = buf[1023];
    __syncthreads();
    if (tid == 0) carry_s = c0 + tot;
    __syncthreads();
  }
  if (tid == 0) ptr[M] = total;
}

// ---- bin edges by destination tile ----
__global__ __launch_bounds__(256) void rgc_fill(
    const int* __restrict__ src, const int* __restrict__ dst,
    const int* __restrict__ tptr, int* __restrict__ tfill,
    int2* __restrict__ edges, int E, int ntiles, int rel0)
{
  int g = blockIdx.y;
  int e = blockIdx.x * 256 + threadIdx.x;
  if (e >= E) return;
  int d = dst[(size_t)(rel0 + g) * E + e];
  int bin = g * ntiles + (d >> 6);
  int pos = tptr[bin] + atomicAdd(&tfill[bin], 1);
  edges[pos] = make_int2(src[(size_t)(rel0 + g) * E + e], d & 63);
}

// ---- aggregation: gather -> mean -> pre-swizzled bf16 tile into Ahat ----
__global__ __launch_bounds__(256) void rgc_agg(
    const float* __restrict__ x, const int* __restrict__ degc,
    const int* __restrict__ tptr, const int2* __restrict__ edges,
    unsigned short* __restrict__ Ahat, int N, int ntiles, int G)
{
  __shared__ float inl[TN * D];  // 32 KB fp32 accumulation tile
  __shared__ int2 ebuf[256];     // 2 KB staged edges
  __shared__ float scl[TN];

  int tx = threadIdx.x;
  int tile = blockIdx.x;
  int g = blockIdx.y;
  int node0 = tile * TN;

#pragma unroll
  for (int i = 0; i < 8; i++)
    ((float4*)inl)[tx + i * 256] = make_float4(0.f, 0.f, 0.f, 0.f);
  if (tx < TN) {
    int node = node0 + tx;
    float dg = (node < N) ? (float)degc[(size_t)g * N + node] : 0.f;
    scl[tx] = 1.0f / fmaxf(dg, 1.0f);
  }

  int bin = g * ntiles + tile;
  int e0 = tptr[bin], e1 = tptr[bin + 1];
  int grp = tx >> 4, c = tx & 15;
  for (int base = e0; base < e1; base += 256) {
    int cnt = min(256, e1 - base);
    __syncthreads();  // inl zero / previous ebuf reads done
    if (tx < cnt) ebuf[tx] = edges[base + tx];
    __syncthreads();
    for (int j = grp; j < cnt; j += 16) {
      int2 ed = ebuf[j];
      const float4* xp = (const float4*)(x + (size_t)ed.x * D);
      float4 v0 = xp[2 * c], v1 = xp[2 * c + 1];
      float* p = &inl[ed.y * D + 8 * c];
      atomicAdd(p + 0, v0.x); atomicAdd(p + 1, v0.y);
      atomicAdd(p + 2, v0.z); atomicAdd(p + 3, v0.w);
      atomicAdd(p + 4, v1.x); atomicAdd(p + 5, v1.y);
      atomicAdd(p + 6, v1.z); atomicAdd(p + 7, v1.w);
    }
  }
  __syncthreads();

  // convert+scale -> swizzled bf16 image, linear 16 KB store
  char* dstp = (char*)(Ahat + ((size_t)tile * G + g) * (TN * D));
#pragma unroll
  for (int it = 0; it < 4; it++) {
    int i = tx + it * 256;
    int row = i >> 4, c16 = i & 15;
    float sc = scl[row];
    float4 v0 = ((float4*)inl)[i * 2];
    float4 v1 = ((float4*)inl)[i * 2 + 1];
    uint4 u;
    u.x = bf16rne(v0.x * sc) | (bf16rne(v0.y * sc) << 16);
    u.y = bf16rne(v0.z * sc) | (bf16rne(v0.w * sc) << 16);
    u.z = bf16rne(v1.x * sc) | (bf16rne(v1.y * sc) << 16);
    u.w = bf16rne(v1.z * sc) | (bf16rne(v1.w * sc) << 16);
    unsigned int off =
        ((unsigned int)(row * 256 + c16 * 16)) ^ (((unsigned int)(row & 7)) << 4);
    *(uint4*)(dstp + off) = u;
  }
}

// ---- GEMM: out_tile = [relu](prior + sum_s Ahat_s @ W_s [+ x @ loopW]) ----
__global__ __launch_bounds__(256) void rgc_gemm(
    const float* __restrict__ x, const unsigned short* __restrict__ WT,
    const unsigned short* __restrict__ Ahat, float* __restrict__ out,
    int N, int Gpass, int rel0, int R, int flags)
{
  __shared__ char Ab[TN * D * 2];  // 16 KB
  __shared__ char Wb[D * D * 2];   // 32 KB

  int tx = threadIdx.x;
  int tile = blockIdx.x;
  int node0 = tile * TN;
  int lane = tx & 63;
  int w = tx >> 6;

  f32x4 acc[8];
#pragma unroll
  for (int i = 0; i < 8; i++) acc[i] = (f32x4){0.f, 0.f, 0.f, 0.f};

  int S = Gpass + ((flags & 2) ? 1 : 0);
  for (int s = 0; s < S; s++) {
    bool is_loop = (s == Gpass);
    int widx = is_loop ? R : (rel0 + s);
    if (!is_loop) {
      const float4* asrc = (const float4*)(Ahat + ((size_t)tile * Gpass + s) * (TN * D));
#pragma unroll
      for (int i = 0; i < 4; i++)
        ((float4*)Ab)[tx + i * 256] = asrc[tx + i * 256];
    } else {
#pragma unroll
      for (int it = 0; it < 4; it++) {
        int i = tx + it * 256;
        int row = i >> 4, c16 = i & 15;
        int node = node0 + row;
        uint4 u = make_uint4(0, 0, 0, 0);
        if (node < N) {
          const float4* xp = (const float4*)(x + (size_t)node * D);
          float4 v0 = xp[c16 * 2], v1 = xp[c16 * 2 + 1];
          u.x = bf16rne(v0.x) | (bf16rne(v0.y) << 16);
          u.y = bf16rne(v0.z) | (bf16rne(v0.w) << 16);
          u.z = bf16rne(v1.x) | (bf16rne(v1.y) << 16);
          u.w = bf16rne(v1.z) | (bf16rne(v1.w) << 16);
        }
        unsigned int off =
            ((unsigned int)(row * 256 + c16 * 16)) ^ (((unsigned int)(row & 7)) << 4);
        *(uint4*)(Ab + off) = u;
      }
    }
    const float4* wsrc = (const float4*)(WT + (size_t)widx * D * D);
#pragma unroll
    for (int i = 0; i < 8; i++)
      ((float4*)Wb)[tx + i * 256] = wsrc[tx + i * 256];
    __syncthreads();

    int rA = w * 16 + (lane & 15);
    unsigned int mA = (unsigned int)((rA & 7) << 4);
    unsigned int kof = (unsigned int)((lane >> 4) * 16);
    short8 afr[4];
#pragma unroll
    for (int kk = 0; kk < 4; kk++)
      afr[kk] = *(const short8*)(Ab + rA * 256 + (((unsigned int)(kk * 64) + kof) ^ mA));
#pragma unroll
    for (int ct = 0; ct < 8; ct++) {
      int rB = ct * 16 + (lane & 15);
      unsigned int mB = (unsigned int)((rB & 7) << 4);
#pragma unroll
      for (int kk = 0; kk < 4; kk++) {
        short8 b = *(const short8*)(Wb + rB * 256 + (((unsigned int)(kk * 64) + kof) ^ mB));
        acc[ct] = __builtin_amdgcn_mfma_f32_16x16x32_bf16(afr[kk], b, acc[ct], 0, 0, 0);
      }
    }
    __syncthreads();
  }

  // epilogue (C/D: col=lane&15, row=(lane>>4)*4+reg)
  int colb = lane & 15;
  int rowb = (lane >> 4) * 4;
#pragma unroll
  for (int ct = 0; ct < 8; ct++) {
#pragma unroll
    for (int j = 0; j < 4; j++) {
      int node = node0 + w * 16 + rowb + j;
      if (node >= N) continue;
      float* op = out + (size_t)node * D + ct * 16 + colb;
      float r = acc[ct][j];
      if (!(flags & 1)) r += *op;
      if (flags & 2) r = fmaxf(r, 0.f);
      *op = r;
    }
  }
}

extern "C" void kernel_launch(void* const* d_in, const int* in_sizes, int n_in,
                              void* d_out, int out_size, void* d_ws, size_t ws_size,
                              hipStream_t stream)
{
  const float* x     = (const float*)d_in[0];
  const float* W     = (const float*)d_in[1];
  const float* loopW = (const float*)d_in[2];
  const int*   src   = (const int*)d_in[3];
  const int*   dst   = (const int*)d_in[4];
  float* out = (float*)d_out;

  int N = in_sizes[0] / D;        // 100000
  int R = in_sizes[1] / (D * D);  // 4
  int E = in_sizes[3] / R;        // 160000
  int ntiles = (N + TN - 1) / TN;

  // fixed layout (R-sized), 16B-aligned sections:
  // degc[R*N] | tcnt[R*nt] | tfill[R*nt] | tptr[R*nt+1] | edges int2[R*E] | WT | Ahat
  size_t o_degc  = 0;
  size_t o_tcnt  = (o_degc + (size_t)R * N * 4 + 15) & ~(size_t)15;
  size_t o_tfill = (o_tcnt + (size_t)R * ntiles * 4 + 15) & ~(size_t)15;
  size_t o_tptr  = (o_tfill + (size_t)R * ntiles * 4 + 15) & ~(size_t)15;
  size_t o_edge  = (o_tptr + ((size_t)R * ntiles + 1) * 4 + 15) & ~(size_t)15;
  size_t o_wt    = (o_edge + (size_t)R * E * 8 + 15) & ~(size_t)15;
  size_t o_ahat  = (o_wt + (size_t)(R + 1) * D * D * 2 + 15) & ~(size_t)15;

  char* wsb = (char*)d_ws;
  int*  degc  = (int*)(wsb + o_degc);
  int*  tcnt  = (int*)(wsb + o_tcnt);
  int*  tfill = (int*)(wsb + o_tfill);
  int*  tptr  = (int*)(wsb + o_tptr);
  int2* edges = (int2*)(wsb + o_edge);
  unsigned short* WT   = (unsigned short*)(wsb + o_wt);
  unsigned short* Ahat = (unsigned short*)(wsb + o_ahat);

  // relation group size that fits Ahat in remaining workspace
  int G = R;
  while (G > 1 && o_ahat + (size_t)ntiles * G * TN * D * 2 > ws_size) G--;

  rgc_prep_w<<<((R + 1) * D * D + 255) / 256, 256, 0, stream>>>(W, loopW, WT, R);

  for (int rel0 = 0; rel0 < R; rel0 += G) {
    int g = (R - rel0 < G) ? (R - rel0) : G;
    hipMemsetAsync(wsb + o_degc, 0, o_tptr - o_degc, stream);
    dim3 egrid((E + 255) / 256, g);
    rgc_hist<<<egrid, 256, 0, stream>>>(dst, degc, tcnt, N, E, ntiles, rel0);
    rgc_scan<<<1, 1024, 0, stream>>>(tcnt, tptr, g * ntiles, g * E);
    rgc_fill<<<egrid, 256, 0, stream>>>(src, dst, tptr, tfill, edges, E, ntiles, rel0);
    dim3 agrid(ntiles, g);
    rgc_agg<<<agrid, 256, 0, stream>>>(x, degc, tptr, edges, Ahat, N, ntiles, g);
    int flags = (rel0 == 0 ? 1 : 0) | (rel0 + g >= R ? 2 : 0);
    rgc_gemm<<<ntiles, 256, 0, stream>>>(x, WT, Ahat, out, N, g, rel0, R, flags);
  }
}

// Round 5
// 249.203 us; speedup vs baseline: 6.2081x; 2.6381x over previous
//
#include <hip/hip_runtime.h>

#define D 128
#define TN 64

typedef __attribute__((ext_vector_type(8))) short short8;
typedef __attribute__((ext_vector_type(4))) float f32x4;

__device__ __forceinline__ unsigned int bf16rne(float f) {
  unsigned int b = __float_as_uint(f);
  return (b + 0x7fffu + ((b >> 16) & 1u)) >> 16;
}
__device__ __forceinline__ float bf2f(unsigned int u) {
  return __uint_as_float(u << 16);
}

// ---- one-time: W[r][k][c] (+loopW at R) -> bf16, transposed [c][k], XOR-swizzled ----
__global__ __launch_bounds__(256) void rgc_prep_w(
    const float* __restrict__ W, const float* __restrict__ loopW,
    unsigned short* __restrict__ WT, int R)
{
  int tid = blockIdx.x * 256 + threadIdx.x;
  int s = tid >> 14;
  if (s > R) return;
  int rem = tid & 16383;
  int k = rem >> 7;
  int c = rem & 127;
  float v = (s < R) ? W[(size_t)s * D * D + k * D + c] : loopW[k * D + c];
  unsigned int u = bf16rne(v);
  unsigned int off = ((unsigned int)(c * D + k) * 2u) ^ (((unsigned int)(c & 7)) << 4);
  *(unsigned short*)((char*)WT + (size_t)s * D * D * 2 + off) = (unsigned short)u;
}

// ---- one-time: x -> bf16 row-major ----
__global__ __launch_bounds__(256) void rgc_prep_x(
    const float* __restrict__ x, unsigned short* __restrict__ xb, long long total8)
{
  long long i = (long long)blockIdx.x * 256 + threadIdx.x;  // 8 elems per thread
  if (i >= total8) return;
  float4 v0 = ((const float4*)x)[i * 2];
  float4 v1 = ((const float4*)x)[i * 2 + 1];
  uint4 u;
  u.x = bf16rne(v0.x) | (bf16rne(v0.y) << 16);
  u.y = bf16rne(v0.z) | (bf16rne(v0.w) << 16);
  u.z = bf16rne(v1.x) | (bf16rne(v1.y) << 16);
  u.w = bf16rne(v1.z) | (bf16rne(v1.w) << 16);
  ((uint4*)xb)[i] = u;
}

// ---- histograms: per-node degree + per-tile counts ----
__global__ __launch_bounds__(256) void rgc_hist(
    const int* __restrict__ dst, int* __restrict__ degc, int* __restrict__ tcnt,
    int N, int E, int ntiles, int rel0)
{
  int g = blockIdx.y;
  int e = blockIdx.x * 256 + threadIdx.x;
  if (e >= E) return;
  int d = dst[(size_t)(rel0 + g) * E + e];
  atomicAdd(&degc[(size_t)g * N + d], 1);
  atomicAdd(&tcnt[g * ntiles + (d >> 6)], 1);
}

// ---- exclusive scan over M bin counts (single block; M <= 8192) ----
__global__ __launch_bounds__(1024) void rgc_scan(
    const int* __restrict__ cnt, int* __restrict__ ptr, int M, int total)
{
  __shared__ int buf[1024];
  int tid = threadIdx.x;
  int v[8];
  int s = 0;
#pragma unroll
  for (int j = 0; j < 8; j++) {
    int i = tid * 8 + j;
    v[j] = (i < M) ? cnt[i] : 0;
    s += v[j];
  }
  buf[tid] = s;
  __syncthreads();
  for (int off = 1; off < 1024; off <<= 1) {
    int t = (tid >= off) ? buf[tid - off] : 0;
    __syncthreads();
    buf[tid] += t;
    __syncthreads();
  }
  int run = buf[tid] - s;
#pragma unroll
  for (int j = 0; j < 8; j++) {
    int i = tid * 8 + j;
    if (i < M) ptr[i] = run;
    run += v[j];
  }
  if (tid == 0) ptr[M] = total;
}

// ---- per-node offsets: nodeptr = tptr[bin] + within-tile exclusive scan of degc ----
__global__ __launch_bounds__(256) void rgc_nodeptr(
    const int* __restrict__ degc, const int* __restrict__ tptr,
    int* __restrict__ nodeptr, int N, int ntiles, int nbins)
{
  int wv = threadIdx.x >> 6;
  int lane = threadIdx.x & 63;
  int bin = blockIdx.x * 4 + wv;
  if (bin >= nbins) return;
  int grel = bin / ntiles;
  int tile = bin - grel * ntiles;
  int node = tile * TN + lane;
  int deg = (node < N) ? degc[(size_t)grel * N + node] : 0;
  int v = deg;
#pragma unroll
  for (int off = 1; off < 64; off <<= 1) {
    int t = __shfl_up(v, off, 64);
    if (lane >= off) v += t;
  }
  if (node < N) nodeptr[(size_t)grel * N + node] = tptr[bin] + (v - deg);
}

// ---- scatter src ids into node-contiguous lists ----
__global__ __launch_bounds__(256) void rgc_fill(
    const int* __restrict__ src, const int* __restrict__ dst,
    const int* __restrict__ nodeptr, int* __restrict__ nfill,
    int* __restrict__ esrc, int N, int E, int rel0)
{
  int g = blockIdx.y;
  int e = blockIdx.x * 256 + threadIdx.x;
  if (e >= E) return;
  int d = dst[(size_t)(rel0 + g) * E + e];
  int pos = nodeptr[(size_t)g * N + d] + atomicAdd(&nfill[(size_t)g * N + d], 1);
  esrc[pos] = src[(size_t)(rel0 + g) * E + e];
}

// ---- aggregation: register-only gather -> mean -> swizzled bf16 Ahat tile ----
__global__ __launch_bounds__(256) void rgc_agg(
    const unsigned short* __restrict__ xb, const int* __restrict__ degc,
    const int* __restrict__ nodeptr, const int* __restrict__ esrc,
    unsigned short* __restrict__ Ahat, int N, int ntiles, int G)
{
  int tx = threadIdx.x;
  int tile = blockIdx.x;
  int g = blockIdx.y;
  int grp = tx >> 4, c = tx & 15;
  char* dstp = (char*)(Ahat + ((size_t)tile * G + g) * (TN * D));

#pragma unroll
  for (int t = 0; t < 4; t++) {
    int row = grp * 4 + t;
    int node = tile * TN + row;
    float acc[8];
#pragma unroll
    for (int k = 0; k < 8; k++) acc[k] = 0.f;
    int deg = 0;
    if (node < N) {
      deg = degc[(size_t)g * N + node];
      int start = nodeptr[(size_t)g * N + node];
      for (int j = 0; j < deg; j++) {
        int s = esrc[start + j];
        uint4 u = ((const uint4*)(xb + (size_t)s * D))[c];
        acc[0] += bf2f(u.x & 0xffffu); acc[1] += bf2f(u.x >> 16);
        acc[2] += bf2f(u.y & 0xffffu); acc[3] += bf2f(u.y >> 16);
        acc[4] += bf2f(u.z & 0xffffu); acc[5] += bf2f(u.z >> 16);
        acc[6] += bf2f(u.w & 0xffffu); acc[7] += bf2f(u.w >> 16);
      }
    }
    float sc = 1.0f / fmaxf((float)deg, 1.0f);
    uint4 o;
    o.x = bf16rne(acc[0] * sc) | (bf16rne(acc[1] * sc) << 16);
    o.y = bf16rne(acc[2] * sc) | (bf16rne(acc[3] * sc) << 16);
    o.z = bf16rne(acc[4] * sc) | (bf16rne(acc[5] * sc) << 16);
    o.w = bf16rne(acc[6] * sc) | (bf16rne(acc[7] * sc) << 16);
    unsigned int off =
        ((unsigned int)(row * 256 + c * 16)) ^ (((unsigned int)(row & 7)) << 4);
    *(uint4*)(dstp + off) = o;
  }
}

// ---- GEMM: out_tile = [relu](prior + sum_s Ahat_s @ W_s [+ xb @ loopW]) ----
__global__ __launch_bounds__(256) void rgc_gemm(
    const unsigned short* __restrict__ xb, const unsigned short* __restrict__ WT,
    const unsigned short* __restrict__ Ahat, float* __restrict__ out,
    int N, int Gpass, int rel0, int R, int flags)
{
  __shared__ char Ab[TN * D * 2];  // 16 KB
  __shared__ char Wb[D * D * 2];   // 32 KB

  int tx = threadIdx.x;
  int tile = blockIdx.x;
  int node0 = tile * TN;
  int lane = tx & 63;
  int w = tx >> 6;

  f32x4 acc[8];
#pragma unroll
  for (int i = 0; i < 8; i++) acc[i] = (f32x4){0.f, 0.f, 0.f, 0.f};

  int S = Gpass + ((flags & 2) ? 1 : 0);
  for (int s = 0; s < S; s++) {
    bool is_loop = (s == Gpass);
    int widx = is_loop ? R : (rel0 + s);
    if (!is_loop) {
      const float4* asrc = (const float4*)(Ahat + ((size_t)tile * Gpass + s) * (TN * D));
#pragma unroll
      for (int i = 0; i < 4; i++)
        ((float4*)Ab)[tx + i * 256] = asrc[tx + i * 256];
    } else {
#pragma unroll
      for (int it = 0; it < 4; it++) {
        int i = tx + it * 256;
        int row = i >> 4, c16 = i & 15;
        int node = node0 + row;
        uint4 u = make_uint4(0, 0, 0, 0);
        if (node < N) u = ((const uint4*)(xb + (size_t)node * D))[c16];
        unsigned int off =
            ((unsigned int)(row * 256 + c16 * 16)) ^ (((unsigned int)(row & 7)) << 4);
        *(uint4*)(Ab + off) = u;
      }
    }
    const float4* wsrc = (const float4*)(WT + (size_t)widx * D * D);
#pragma unroll
    for (int i = 0; i < 8; i++)
      ((float4*)Wb)[tx + i * 256] = wsrc[tx + i * 256];
    __syncthreads();

    int rA = w * 16 + (lane & 15);
    unsigned int mA = (unsigned int)((rA & 7) << 4);
    unsigned int kof = (unsigned int)((lane >> 4) * 16);
    short8 afr[4];
#pragma unroll
    for (int kk = 0; kk < 4; kk++)
      afr[kk] = *(const short8*)(Ab + rA * 256 + (((unsigned int)(kk * 64) + kof) ^ mA));
#pragma unroll
    for (int ct = 0; ct < 8; ct++) {
      int rB = ct * 16 + (lane & 15);
      unsigned int mB = (unsigned int)((rB & 7) << 4);
#pragma unroll
      for (int kk = 0; kk < 4; kk++) {
        short8 b = *(const short8*)(Wb + rB * 256 + (((unsigned int)(kk * 64) + kof) ^ mB));
        acc[ct] = __builtin_amdgcn_mfma_f32_16x16x32_bf16(afr[kk], b, acc[ct], 0, 0, 0);
      }
    }
    __syncthreads();
  }

  int colb = lane & 15;
  int rowb = (lane >> 4) * 4;
#pragma unroll
  for (int ct = 0; ct < 8; ct++) {
#pragma unroll
    for (int j = 0; j < 4; j++) {
      int node = node0 + w * 16 + rowb + j;
      if (node >= N) continue;
      float* op = out + (size_t)node * D + ct * 16 + colb;
      float r = acc[ct][j];
      if (!(flags & 1)) r += *op;
      if (flags & 2) r = fmaxf(r, 0.f);
      *op = r;
    }
  }
}

extern "C" void kernel_launch(void* const* d_in, const int* in_sizes, int n_in,
                              void* d_out, int out_size, void* d_ws, size_t ws_size,
                              hipStream_t stream)
{
  const float* x     = (const float*)d_in[0];
  const float* W     = (const float*)d_in[1];
  const float* loopW = (const float*)d_in[2];
  const int*   src   = (const int*)d_in[3];
  const int*   dst   = (const int*)d_in[4];
  float* out = (float*)d_out;

  int N = in_sizes[0] / D;        // 100000
  int R = in_sizes[1] / (D * D);  // 4
  int E = in_sizes[3] / R;        // 160000
  int ntiles = (N + TN - 1) / TN;

  // layout: degc | nfill | tcnt | tptr | nodeptr | esrc | WT | xb | Ahat
  size_t o_degc  = 0;
  size_t o_nfill = (o_degc + (size_t)R * N * 4 + 15) & ~(size_t)15;
  size_t o_tcnt  = (o_nfill + (size_t)R * N * 4 + 15) & ~(size_t)15;
  size_t o_tptr  = (o_tcnt + (size_t)R * ntiles * 4 + 15) & ~(size_t)15;
  size_t o_np    = (o_tptr + ((size_t)R * ntiles + 1) * 4 + 15) & ~(size_t)15;
  size_t o_esrc  = (o_np + (size_t)R * N * 4 + 15) & ~(size_t)15;
  size_t o_wt    = (o_esrc + (size_t)R * E * 4 + 15) & ~(size_t)15;
  size_t o_xb    = (o_wt + (size_t)(R + 1) * D * D * 2 + 15) & ~(size_t)15;
  size_t o_ahat  = (o_xb + (size_t)N * D * 2 + 15) & ~(size_t)15;

  char* wsb = (char*)d_ws;
  int*  degc    = (int*)(wsb + o_degc);
  int*  nfill   = (int*)(wsb + o_nfill);
  int*  tcnt    = (int*)(wsb + o_tcnt);
  int*  tptr    = (int*)(wsb + o_tptr);
  int*  nodeptr = (int*)(wsb + o_np);
  int*  esrc    = (int*)(wsb + o_esrc);
  unsigned short* WT   = (unsigned short*)(wsb + o_wt);
  unsigned short* xb   = (unsigned short*)(wsb + o_xb);
  unsigned short* Ahat = (unsigned short*)(wsb + o_ahat);

  int G = R;
  while (G > 1 && o_ahat + (size_t)ntiles * G * TN * D * 2 > ws_size) G--;

  rgc_prep_w<<<((R + 1) * D * D + 255) / 256, 256, 0, stream>>>(W, loopW, WT, R);
  long long total8 = (long long)N * D / 8;
  rgc_prep_x<<<(int)((total8 + 255) / 256), 256, 0, stream>>>(x, xb, total8);

  for (int rel0 = 0; rel0 < R; rel0 += G) {
    int g = (R - rel0 < G) ? (R - rel0) : G;
    hipMemsetAsync(wsb + o_degc, 0, o_np - o_degc, stream);
    dim3 egrid((E + 255) / 256, g);
    rgc_hist<<<egrid, 256, 0, stream>>>(dst, degc, tcnt, N, E, ntiles, rel0);
    int nbins = g * ntiles;
    rgc_scan<<<1, 1024, 0, stream>>>(tcnt, tptr, nbins, g * E);
    rgc_nodeptr<<<(nbins + 3) / 4, 256, 0, stream>>>(degc, tptr, nodeptr, N, ntiles, nbins);
    rgc_fill<<<egrid, 256, 0, stream>>>(src, dst, nodeptr, nfill, esrc, N, E, rel0);
    dim3 agrid(ntiles, g);
    rgc_agg<<<agrid, 256, 0, stream>>>(xb, degc, nodeptr, esrc, Ahat, N, ntiles, g);
    int flags = (rel0 == 0 ? 1 : 0) | (rel0 + g >= R ? 2 : 0);
    rgc_gemm<<<ntiles, 256, 0, stream>>>(xb, WT, Ahat, out, N, g, rel0, R, flags);
  }
}